// Round 14
// baseline (158.907 us; speedup 1.0000x reference)
//
#include <hip/hip_runtime.h>

typedef unsigned short u16;
typedef short s16x8 __attribute__((ext_vector_type(8)));
typedef float f32x4 __attribute__((ext_vector_type(4)));

// ---------- scalar dtype helpers ----------
__device__ __forceinline__ u16 f2bf(float f) {
    union { float f; unsigned u; } v; v.f = f;
    unsigned r = v.u + 0x7FFFu + ((v.u >> 16) & 1u);   // RNE
    return (u16)(r >> 16);
}
__device__ __forceinline__ float bf2f(u16 h) {
    union { unsigned u; float f; } v; v.u = ((unsigned)h) << 16;
    return v.f;
}
__device__ __forceinline__ u16 f2h(float f) {
    _Float16 h = (_Float16)f;
    union { _Float16 h; u16 u; } v; v.h = h; return v.u;
}
__device__ __forceinline__ float h2f(u16 u) {
    union { u16 u; _Float16 h; } v; v.u = u; return (float)v.h;
}

// async global->LDS, 16B per lane; LDS dest = wave-uniform base + lane*16
__device__ __forceinline__ void gl_lds16(const u16* g, u16* l) {
    __builtin_amdgcn_global_load_lds(
        (const __attribute__((address_space(1))) void*)g,
        (__attribute__((address_space(3))) void*)l,
        16, 0, 0);
}

// BK=64 swizzled LDS fragment read (R4-R13 verified): row-major [row][64 u16],
// byte col cb = ((kk<<6)+(fq<<4)) ^ ((row&7)<<4).
__device__ __forceinline__ s16x8 ldfrag(const u16* base, int row, int kk, int fq) {
    int cb = ((kk << 6) + (fq << 4)) ^ ((row & 7) << 4);
    return *reinterpret_cast<const s16x8*>(base + row * 64 + (cb >> 1));
}

#define MFMA16(a, b, c) __builtin_amdgcn_mfma_f32_16x16x32_bf16((a), (b), (c), 0, 0, 0)

// ---------- fused prep: convert x, convert w, build trig table ----------
__global__ __launch_bounds__(256)
void prep(const float* __restrict__ x, const float* __restrict__ w,
          u16* __restrict__ xb, u16* __restrict__ wb, u16* __restrict__ trig) {
    const int bid = blockIdx.x;
    if (bid < 2048) {
        int i = (bid * 256 + threadIdx.x) * 4;
        const int stride = 2048 * 256 * 4;
        for (; i < 8192 * 1024; i += stride) {
            float4 v = *reinterpret_cast<const float4*>(x + i);
            ushort4 o;
            o.x = f2bf(v.x); o.y = f2bf(v.y); o.z = f2bf(v.z); o.w = f2bf(v.w);
            *reinterpret_cast<ushort4*>(xb + i) = o;
        }
    } else if (bid < 2816) {
        int i = ((bid - 2048) * 256 + threadIdx.x) * 4;
        const int stride = 768 * 256 * 4;
        for (; i < 3072 * 1024; i += stride) {
            float4 v = *reinterpret_cast<const float4*>(w + i);
            ushort4 o;
            o.x = f2bf(v.x); o.y = f2bf(v.y); o.z = f2bf(v.z); o.w = f2bf(v.w);
            *reinterpret_cast<ushort4*>(wb + i) = o;
        }
    } else {
        const int t = bid - 2816;
        const float L = 0.025952563241307517f;  // log2(10000)/512
        u16* row = trig + (size_t)t * 1024;
#pragma unroll
        for (int i = 0; i < 2; ++i) {
            int d = threadIdx.x + i * 256;
            float invf = exp2f(-(float)d * L);
            float ang = (float)t * invf;
            float s, c;
            sincosf(ang, &s, &c);
            row[d] = f2h(c);
            row[512 + d] = f2h(s);
        }
    }
}

// ================= unified bf16 GEMM, C = A @ B^T =================
// 128x128 tile, 4 waves (256 thr), wave tile 64x64 (acc[4][4]), BK=64,
// double-buffered LDS (64KB -> 2 blocks/CU), 2-phase schedule, XOR-swizzle.
// MODE 0: QKV, grid 1536 1D XCD-banded; col<2048 -> qk[8192][2048], else VT direct.
// MODE 1: S -> P' = exp(32*s - 32) causal-masked bf16, + per-row partial sums
//         into psum[4][32][2048] (slot = bx*2 + (wave&1)). Grid (16,16,4), skip bx>by.
//         Fixed max 32 is exact: Q,K rows are L2-normalized (scores in [-32,32]).
// MODE 2: PV, grid (8,64): y decodes (batch=y&3, rowtile=15-(y>>2)), longest-first,
//         kend=(rowtile+1)*128; epilogue scales by rowinv[b][row].
template <int MODE, typename CT>
__global__ __launch_bounds__(256, 2)
void gemm_bt(const u16* __restrict__ A, const u16* __restrict__ B, CT* __restrict__ C,
             u16* __restrict__ VT, float* __restrict__ psum, const float* __restrict__ rowinv,
             int K, int lda, int ldb, int ldc, long sA, long sB, long sC) {
    int bx, by, bz;
    if (MODE == 0) {
        int bid = blockIdx.x;              // 1536 blocks; HW: xcd = bid % 8
        int xcd = bid & 7, idx = bid >> 3; // 192 per XCD
        int r = idx >> 6, w2 = idx & 63;   // 3 regions of 8bx x 8by
        bx = r * 8 + (w2 & 7);
        by = xcd * 8 + (w2 >> 3);
        bz = 0;
    } else {
        bx = blockIdx.x; by = blockIdx.y; bz = blockIdx.z;
    }
    if (MODE == 1 && bx > by) return;
    if (MODE == 2) { bz = blockIdx.y & 3; by = 15 - (int)(blockIdx.y >> 2); }
    A += (size_t)bz * sA; B += (size_t)bz * sB; C += (size_t)bz * sC;
    int kend = K;
    if (MODE == 2) { int kl = (by + 1) * 128; kend = kl < K ? kl : K; }
    const int NT = kend >> 6;              // K-steps of 64

    __shared__ u16 lds[32768];             // 2 bufs x [A 8192 u16 | B 8192 u16]

    const int tid  = threadIdx.x;
    const int lane = tid & 63;
    const int wave = tid >> 6;             // 0..3
    const int wr = (wave >> 1) * 64;       // 0 or 64
    const int wc = (wave & 1) * 64;        // 0 or 64
    const int fr = lane & 15;
    const int fq = lane >> 4;
    const int tm = by * 128, tn = bx * 128;

    // staging: 8 x 16B per thread per K-step (4 A + 4 B chunks of 32 rows),
    // pre-swizzled source col (both-sides rule).
    const int srow = tid >> 3;                                  // 0..31
    const int gco  = (((tid & 7) ^ (srow & 7)) << 3);           // u16 col
    const u16* aR[4]; const u16* bR[4];
#pragma unroll
    for (int j = 0; j < 4; ++j) {
        aR[j] = A + (size_t)(tm + j * 32 + srow) * lda + gco;
        bR[j] = B + (size_t)(tn + j * 32 + srow) * ldb + gco;
    }

#define STAGE(b2, k0) do {                                                        \
    _Pragma("unroll") for (int j = 0; j < 4; ++j)                                 \
        gl_lds16(aR[j] + (k0), lds + (b2) * 16384 + j * 2048 + tid * 8);          \
    _Pragma("unroll") for (int j = 0; j < 4; ++j)                                 \
        gl_lds16(bR[j] + (k0), lds + (b2) * 16384 + 8192 + j * 2048 + tid * 8);   \
  } while (0)

    f32x4 acc[4][4];
#pragma unroll
    for (int m = 0; m < 4; ++m)
#pragma unroll
        for (int n = 0; n < 4; ++n) acc[m][n] = {0.f, 0.f, 0.f, 0.f};

    STAGE(0, 0);
    if (NT > 1) STAGE(1, 64);

    for (int t = 0; t < NT; ++t) {
        const int buf = t & 1;
        if (t + 1 < NT) { asm volatile("s_waitcnt vmcnt(8)" ::: "memory"); }
        else            { asm volatile("s_waitcnt vmcnt(0)" ::: "memory"); }
        __builtin_amdgcn_s_barrier();
        __builtin_amdgcn_sched_barrier(0);

        const u16* Ab = lds + buf * 16384;
        const u16* Bb = Ab + 8192;
        s16x8 bf0[4], bf1[4];
#pragma unroll
        for (int n = 0; n < 4; ++n) {
            bf0[n] = ldfrag(Bb, wc + n * 16 + fr, 0, fq);
            bf1[n] = ldfrag(Bb, wc + n * 16 + fr, 1, fq);
        }
        __builtin_amdgcn_s_setprio(1);
#pragma unroll
        for (int m = 0; m < 4; ++m) {
            s16x8 a0 = ldfrag(Ab, wr + m * 16 + fr, 0, fq);
            s16x8 a1 = ldfrag(Ab, wr + m * 16 + fr, 1, fq);
#pragma unroll
            for (int n = 0; n < 4; ++n) {
                acc[m][n] = MFMA16(a0, bf0[n], acc[m][n]);
                acc[m][n] = MFMA16(a1, bf1[n], acc[m][n]);
            }
        }
        __builtin_amdgcn_s_setprio(0);
        __builtin_amdgcn_sched_barrier(0);
        __builtin_amdgcn_s_barrier();
        if (t + 2 < NT) STAGE(buf, (t + 2) << 6);
    }
#undef STAGE

    // epilogue: D row=(lane>>4)*4+r, col=lane&15 (m89-verified)
    if (MODE == 0 && tn >= 2048) {
        // V column-tiles: write transposed into VT[b][col-2048][t]
#pragma unroll
        for (int m = 0; m < 4; ++m)
#pragma unroll
            for (int n = 0; n < 4; ++n)
#pragma unroll
                for (int r = 0; r < 4; ++r) {
                    int row = tm + wr + m * 16 + fq * 4 + r;
                    int col = tn + wc + n * 16 + fr;
                    VT[((size_t)(row >> 11)) * 2097152 + (size_t)(col - 2048) * 2048 + (row & 2047)]
                        = f2bf(acc[m][n][r]);
                }
    } else if (MODE == 1) {
        // P' = exp(32*s - 32), causal mask, bf16 store + per-row partial sums.
        u16* P = (u16*)C;
#pragma unroll
        for (int m = 0; m < 4; ++m) {
#pragma unroll
            for (int r = 0; r < 4; ++r) {
                int row = tm + wr + m * 16 + fq * 4 + r;
                float rs = 0.f;
#pragma unroll
                for (int n = 0; n < 4; ++n) {
                    int col = tn + wc + n * 16 + fr;
                    float p = (col <= row) ? __expf(32.f * acc[m][n][r] - 32.f) : 0.f;
                    u16 pb = f2bf(p);
                    P[(size_t)row * 2048 + col] = pb;
                    rs += bf2f(pb);                 // sum the value PV will consume
                }
                // reduce across the 16 fr-lanes (same fq => same row)
                rs += __shfl_xor(rs, 1);
                rs += __shfl_xor(rs, 2);
                rs += __shfl_xor(rs, 4);
                rs += __shfl_xor(rs, 8);
                if (fr == 0)
                    psum[((size_t)bz * 32 + bx * 2 + (wave & 1)) * 2048 + row] = rs;
            }
        }
    } else if (MODE == 2) {
#pragma unroll
        for (int m = 0; m < 4; ++m) {
#pragma unroll
            for (int r = 0; r < 4; ++r) {
                int row = tm + wr + m * 16 + fq * 4 + r;
                float inv = rowinv[(size_t)bz * 2048 + row];
#pragma unroll
                for (int n = 0; n < 4; ++n) {
                    int col = tn + wc + n * 16 + fr;
                    C[(size_t)row * ldc + col] = acc[m][n][r] * inv;
                }
            }
        }
    } else {
#pragma unroll
        for (int m = 0; m < 4; ++m)
#pragma unroll
            for (int n = 0; n < 4; ++n)
#pragma unroll
                for (int r = 0; r < 4; ++r) {
                    int row = tm + wr + m * 16 + fq * 4 + r;
                    int col = tn + wc + n * 16 + fr;
                    C[(size_t)row * ldc + col] = (CT)f2bf(acc[m][n][r]);
                }
    }
}

// ---------- rowinv: 1 / sum of psum slots (deterministic) ----------
__global__ __launch_bounds__(256)
void row_reduce(const float* __restrict__ psum, float* __restrict__ rowinv) {
    const int r = blockIdx.x * 256 + threadIdx.x;   // 0..2047
    const int b = blockIdx.y;
    const int nslots = 2 * ((r >> 7) + 1);
    float s = 0.f;
    for (int j = 0; j < nslots; ++j)
        s += psum[((size_t)b * 32 + j) * 2048 + r];
    rowinv[(size_t)b * 2048 + r] = 1.f / s;
}

// ---------- RoPE + L2 norm * sqk*32, in-place on qk[8192][2048] ----------
__global__ __launch_bounds__(256)
void rope_norm(u16* __restrict__ qk, const float* __restrict__ sqk,
               const u16* __restrict__ trig) {
    const int row = blockIdx.x;        // b*2048 + t
    const int t = row & 2047;
    u16* qp = qk + (size_t)row * 2048;
    u16* kp = qp + 1024;
    const u16* tb = trig + (size_t)t * 1024;
    const int d = threadIdx.x << 1;    // 0,2,...,510

    union U2 { uint u; u16 h[2]; };
    U2 qc0, qc1, kc0, kc1, cc, ss;
    qc0.u = *reinterpret_cast<const uint*>(qp + d);
    qc1.u = *reinterpret_cast<const uint*>(qp + 512 + d);
    kc0.u = *reinterpret_cast<const uint*>(kp + d);
    kc1.u = *reinterpret_cast<const uint*>(kp + 512 + d);
    cc.u  = *reinterpret_cast<const uint*>(tb + d);
    ss.u  = *reinterpret_cast<const uint*>(tb + 512 + d);

    float nq0[2], nq1[2], nk0[2], nk1[2];
    float ssq_q = 0.f, ssq_k = 0.f;
#pragma unroll
    for (int j = 0; j < 2; ++j) {
        float c = h2f(cc.h[j]), s = h2f(ss.h[j]);
        float q0 = bf2f(qc0.h[j]), q1 = bf2f(qc1.h[j]);
        float k0 = bf2f(kc0.h[j]), k1 = bf2f(kc1.h[j]);
        nq0[j] = q0 * c - q1 * s;
        nq1[j] = q1 * c + q0 * s;
        nk0[j] = k0 * c - k1 * s;
        nk1[j] = k1 * c + k0 * s;
        ssq_q += nq0[j] * nq0[j] + nq1[j] * nq1[j];
        ssq_k += nk0[j] * nk0[j] + nk1[j] * nk1[j];
    }

#pragma unroll
    for (int off = 32; off; off >>= 1) {
        ssq_q += __shfl_xor(ssq_q, off);
        ssq_k += __shfl_xor(ssq_k, off);
    }
    __shared__ float red[8];
    int wave = threadIdx.x >> 6, lane = threadIdx.x & 63;
    if (lane == 0) { red[wave] = ssq_q; red[4 + wave] = ssq_k; }
    __syncthreads();
    float rq = rsqrtf(red[0] + red[1] + red[2] + red[3]);
    float rk = rsqrtf(red[4] + red[5] + red[6] + red[7]);

    float2 sq0 = *reinterpret_cast<const float2*>(sqk + d);
    float2 sq1 = *reinterpret_cast<const float2*>(sqk + 512 + d);
    float s0[2] = {sq0.x * 32.f, sq0.y * 32.f};
    float s1[2] = {sq1.x * 32.f, sq1.y * 32.f};

    U2 oq0, oq1, ok0, ok1;
#pragma unroll
    for (int j = 0; j < 2; ++j) {
        oq0.h[j] = f2bf(nq0[j] * rq * s0[j]);
        oq1.h[j] = f2bf(nq1[j] * rq * s1[j]);
        ok0.h[j] = f2bf(nk0[j] * rk * s0[j]);
        ok1.h[j] = f2bf(nk1[j] * rk * s1[j]);
    }
    *reinterpret_cast<uint*>(qp + d)       = oq0.u;
    *reinterpret_cast<uint*>(qp + 512 + d) = oq1.u;
    *reinterpret_cast<uint*>(kp + d)       = ok0.u;
    *reinterpret_cast<uint*>(kp + 512 + d) = ok1.u;
}

// ---------- host launcher ----------
extern "C" void kernel_launch(void* const* d_in, const int* in_sizes, int n_in,
                              void* d_out, int out_size, void* d_ws, size_t ws_size,
                              hipStream_t stream) {
    const float* x   = (const float*)d_in[0];   // [4,2048,1024]
    const float* w   = (const float*)d_in[1];   // [3072,1024]
    const float* sqk = (const float*)d_in[2];   // [1024]
    float* out = (float*)d_out;

    const size_t SZ_XB  = (size_t)8192 * 1024 * 2;
    const size_t SZ_WB  = (size_t)3072 * 1024 * 2;
    const size_t SZ_QK  = (size_t)8192 * 2048 * 2;
    const size_t SZ_VT  = (size_t)4 * 1024 * 2048 * 2;
    const size_t SZ_P   = (size_t)4 * 2048 * 2048 * 2;    // P' bf16
    const size_t SZ_TR  = (size_t)2048 * 1024 * 2;
    const size_t SZ_PS  = (size_t)4 * 32 * 2048 * 4;      // psum fp32
    const size_t SZ_RI  = (size_t)4 * 2048 * 4;           // rowinv fp32
    if (ws_size < SZ_XB + SZ_WB + SZ_QK + SZ_VT + SZ_P + SZ_TR + SZ_PS + SZ_RI) return;

    char* ws = (char*)d_ws;
    u16*   xb     = (u16*)ws;   ws += SZ_XB;
    u16*   wb     = (u16*)ws;   ws += SZ_WB;
    u16*   qk     = (u16*)ws;   ws += SZ_QK;
    u16*   VT     = (u16*)ws;   ws += SZ_VT;
    u16*   P      = (u16*)ws;   ws += SZ_P;
    u16*   trig   = (u16*)ws;   ws += SZ_TR;
    float* psum   = (float*)ws; ws += SZ_PS;
    float* rowinv = (float*)ws;

    // fused prep: x->bf16, w->bf16, trig table
    prep<<<4864, 256, 0, stream>>>(x, w, xb, wb, trig);

    // QKV: qk[8192][2048] (Q|K) + VT[b][1024][2048] (V^T direct)
    gemm_bt<0, u16><<<dim3(1536, 1, 1), 256, 0, stream>>>(
        xb, wb, qk, VT, nullptr, nullptr, 1024, 1024, 1024, 2048, 0, 0, 0);

    rope_norm<<<8192, 256, 0, stream>>>(qk, sqk, trig);

    // S -> P' = exp(32s-32) bf16 + psum partial row sums (softmax max fixed at 32)
    gemm_bt<1, u16><<<dim3(16, 16, 4), 256, 0, stream>>>(
        qk, qk + 1024, P, nullptr, psum, nullptr, 1024, 2048, 2048, 2048,
        (long)2048 * 2048, (long)2048 * 2048, (long)2048 * 2048);

    // rowinv = 1 / rowsum
    row_reduce<<<dim3(8, 4), 256, 0, stream>>>(psum, rowinv);

    // out = (P' @ V) * rowinv, longest-first over row tiles
    gemm_bt<2, float><<<dim3(8, 64, 1), 256, 0, stream>>>(
        P, VT, out, nullptr, nullptr, rowinv, 2048, 2048, 2048, 1024,
        (long)2048 * 2048, (long)1024 * 2048, (long)2048 * 1024);
}

// Round 15
// 145.965 us; speedup vs baseline: 1.0887x; 1.0887x over previous
//
#include <hip/hip_runtime.h>

typedef unsigned short u16;
typedef short s16x8 __attribute__((ext_vector_type(8)));
typedef float f32x4 __attribute__((ext_vector_type(4)));

// ---------- scalar dtype helpers ----------
__device__ __forceinline__ u16 f2bf(float f) {
    union { float f; unsigned u; } v; v.f = f;
    unsigned r = v.u + 0x7FFFu + ((v.u >> 16) & 1u);   // RNE
    return (u16)(r >> 16);
}
__device__ __forceinline__ float bf2f(u16 h) {
    union { unsigned u; float f; } v; v.u = ((unsigned)h) << 16;
    return v.f;
}
__device__ __forceinline__ u16 f2h(float f) {
    _Float16 h = (_Float16)f;
    union { _Float16 h; u16 u; } v; v.h = h; return v.u;
}
__device__ __forceinline__ float h2f(u16 u) {
    union { u16 u; _Float16 h; } v; v.u = u; return (float)v.h;
}

// async global->LDS, 16B per lane; LDS dest = wave-uniform base + lane*16
__device__ __forceinline__ void gl_lds16(const u16* g, u16* l) {
    __builtin_amdgcn_global_load_lds(
        (const __attribute__((address_space(1))) void*)g,
        (__attribute__((address_space(3))) void*)l,
        16, 0, 0);
}

// BK=64 swizzled LDS fragment read (R4-R14 verified): row-major [row][64 u16],
// byte col cb = ((kk<<6)+(fq<<4)) ^ ((row&7)<<4).
__device__ __forceinline__ s16x8 ldfrag(const u16* base, int row, int kk, int fq) {
    int cb = ((kk << 6) + (fq << 4)) ^ ((row & 7) << 4);
    return *reinterpret_cast<const s16x8*>(base + row * 64 + (cb >> 1));
}

#define MFMA16(a, b, c) __builtin_amdgcn_mfma_f32_16x16x32_bf16((a), (b), (c), 0, 0, 0)

// ---------- fused prep: convert x, convert w, build trig table ----------
__global__ __launch_bounds__(256)
void prep(const float* __restrict__ x, const float* __restrict__ w,
          u16* __restrict__ xb, u16* __restrict__ wb, u16* __restrict__ trig) {
    const int bid = blockIdx.x;
    if (bid < 2048) {
        int i = (bid * 256 + threadIdx.x) * 4;
        const int stride = 2048 * 256 * 4;
        for (; i < 8192 * 1024; i += stride) {
            float4 v = *reinterpret_cast<const float4*>(x + i);
            ushort4 o;
            o.x = f2bf(v.x); o.y = f2bf(v.y); o.z = f2bf(v.z); o.w = f2bf(v.w);
            *reinterpret_cast<ushort4*>(xb + i) = o;
        }
    } else if (bid < 2816) {
        int i = ((bid - 2048) * 256 + threadIdx.x) * 4;
        const int stride = 768 * 256 * 4;
        for (; i < 3072 * 1024; i += stride) {
            float4 v = *reinterpret_cast<const float4*>(w + i);
            ushort4 o;
            o.x = f2bf(v.x); o.y = f2bf(v.y); o.z = f2bf(v.z); o.w = f2bf(v.w);
            *reinterpret_cast<ushort4*>(wb + i) = o;
        }
    } else {
        const int t = bid - 2816;
        const float L = 0.025952563241307517f;  // log2(10000)/512
        u16* row = trig + (size_t)t * 1024;
#pragma unroll
        for (int i = 0; i < 2; ++i) {
            int d = threadIdx.x + i * 256;
            float invf = exp2f(-(float)d * L);
            float ang = (float)t * invf;
            float s, c;
            sincosf(ang, &s, &c);
            row[d] = f2h(c);
            row[512 + d] = f2h(s);
        }
    }
}

// ================= unified bf16 GEMM, C = A @ B^T =================
// 128x128 tile, 4 waves (256 thr), wave tile 64x64 (acc[4][4]), BK=64,
// double-buffered LDS (64KB -> 2 blocks/CU), 2-phase schedule, XOR-swizzle.
// MODE 0: QKV, grid 1536 1D XCD-banded; col<2048 -> qk[8192][2048], else VT direct.
// MODE 1: S -> P' = exp(32*s-32) causal bf16 + psum partial row sums.
//         Grid 544 1D: xcd=bid&7, batch=xcd>>1 (K-panel 4MB L2-local per XCD pair),
//         triangular decode of (by,bx) from pair-local index. Fixed max 32 is
//         exact: Q,K rows are L2-normalized (scores in [-32,32]).
// MODE 2: PV, grid 512 1D: xcd=bid&7, batch=xcd>>1 (VT-panel L2-local),
//         rt=15-(j>>3) longest-first, kend=(rt+1)*128; epilogue computes rowinv
//         from psum in LDS, scales output.
template <int MODE, typename CT>
__global__ __launch_bounds__(256, 2)
void gemm_bt(const u16* __restrict__ A, const u16* __restrict__ B, CT* __restrict__ C,
             u16* __restrict__ VT, float* __restrict__ psum,
             int K, int lda, int ldb, int ldc, long sA, long sB, long sC) {
    int bx, by, bz;
    if (MODE == 0) {
        int bid = blockIdx.x;              // 1536 blocks; HW: xcd = bid % 8
        int xcd = bid & 7, idx = bid >> 3; // 192 per XCD
        int r = idx >> 6, w2 = idx & 63;   // 3 regions of 8bx x 8by
        bx = r * 8 + (w2 & 7);
        by = xcd * 8 + (w2 >> 3);
        bz = 0;
    } else if (MODE == 1) {
        int bid = blockIdx.x;              // 544 blocks, 68 per XCD
        int xcd = bid & 7;
        bz = xcd >> 1;
        int j = (xcd & 1) * 68 + (bid >> 3);        // 0..135 within batch
        by = (int)((sqrtf(8.f * j + 1.f) - 1.f) * 0.5f);
        while ((by + 1) * (by + 2) / 2 <= j) ++by;
        while (by * (by + 1) / 2 > j) --by;
        bx = j - by * (by + 1) / 2;                 // 0..by
    } else {
        int bid = blockIdx.x;              // 512 blocks, 64 per XCD
        int xcd = bid & 7;
        bz = xcd >> 1;
        int j = (xcd & 1) * 64 + (bid >> 3);        // 0..127 within batch
        by = 15 - (j >> 3);                         // longest-first row tile
        bx = j & 7;
    }
    A += (size_t)bz * sA; B += (size_t)bz * sB; C += (size_t)bz * sC;
    int kend = K;
    if (MODE == 2) { int kl = (by + 1) * 128; kend = kl < K ? kl : K; }
    const int NT = kend >> 6;              // K-steps of 64

    __shared__ u16 lds[32768];             // 2 bufs x [A 8192 u16 | B 8192 u16]

    const int tid  = threadIdx.x;
    const int lane = tid & 63;
    const int wave = tid >> 6;             // 0..3
    const int wr = (wave >> 1) * 64;       // 0 or 64
    const int wc = (wave & 1) * 64;        // 0 or 64
    const int fr = lane & 15;
    const int fq = lane >> 4;
    const int tm = by * 128, tn = bx * 128;

    // staging: 8 x 16B per thread per K-step (4 A + 4 B chunks of 32 rows),
    // pre-swizzled source col (both-sides rule).
    const int srow = tid >> 3;                                  // 0..31
    const int gco  = (((tid & 7) ^ (srow & 7)) << 3);           // u16 col
    const u16* aR[4]; const u16* bR[4];
#pragma unroll
    for (int j = 0; j < 4; ++j) {
        aR[j] = A + (size_t)(tm + j * 32 + srow) * lda + gco;
        bR[j] = B + (size_t)(tn + j * 32 + srow) * ldb + gco;
    }

#define STAGE(b2, k0) do {                                                        \
    _Pragma("unroll") for (int j = 0; j < 4; ++j)                                 \
        gl_lds16(aR[j] + (k0), lds + (b2) * 16384 + j * 2048 + tid * 8);          \
    _Pragma("unroll") for (int j = 0; j < 4; ++j)                                 \
        gl_lds16(bR[j] + (k0), lds + (b2) * 16384 + 8192 + j * 2048 + tid * 8);   \
  } while (0)

    f32x4 acc[4][4];
#pragma unroll
    for (int m = 0; m < 4; ++m)
#pragma unroll
        for (int n = 0; n < 4; ++n) acc[m][n] = {0.f, 0.f, 0.f, 0.f};

    STAGE(0, 0);
    if (NT > 1) STAGE(1, 64);

    for (int t = 0; t < NT; ++t) {
        const int buf = t & 1;
        if (t + 1 < NT) { asm volatile("s_waitcnt vmcnt(8)" ::: "memory"); }
        else            { asm volatile("s_waitcnt vmcnt(0)" ::: "memory"); }
        __builtin_amdgcn_s_barrier();
        __builtin_amdgcn_sched_barrier(0);

        const u16* Ab = lds + buf * 16384;
        const u16* Bb = Ab + 8192;
        s16x8 bf0[4], bf1[4];
#pragma unroll
        for (int n = 0; n < 4; ++n) {
            bf0[n] = ldfrag(Bb, wc + n * 16 + fr, 0, fq);
            bf1[n] = ldfrag(Bb, wc + n * 16 + fr, 1, fq);
        }
        __builtin_amdgcn_s_setprio(1);
#pragma unroll
        for (int m = 0; m < 4; ++m) {
            s16x8 a0 = ldfrag(Ab, wr + m * 16 + fr, 0, fq);
            s16x8 a1 = ldfrag(Ab, wr + m * 16 + fr, 1, fq);
#pragma unroll
            for (int n = 0; n < 4; ++n) {
                acc[m][n] = MFMA16(a0, bf0[n], acc[m][n]);
                acc[m][n] = MFMA16(a1, bf1[n], acc[m][n]);
            }
        }
        __builtin_amdgcn_s_setprio(0);
        __builtin_amdgcn_sched_barrier(0);
        __builtin_amdgcn_s_barrier();
        if (t + 2 < NT) STAGE(buf, (t + 2) << 6);
    }
#undef STAGE

    // epilogue: D row=(lane>>4)*4+r, col=lane&15 (m89-verified)
    if (MODE == 0 && tn >= 2048) {
        // V column-tiles: write transposed into VT[b][col-2048][t]
#pragma unroll
        for (int m = 0; m < 4; ++m)
#pragma unroll
            for (int n = 0; n < 4; ++n)
#pragma unroll
                for (int r = 0; r < 4; ++r) {
                    int row = tm + wr + m * 16 + fq * 4 + r;
                    int col = tn + wc + n * 16 + fr;
                    VT[((size_t)(row >> 11)) * 2097152 + (size_t)(col - 2048) * 2048 + (row & 2047)]
                        = f2bf(acc[m][n][r]);
                }
    } else if (MODE == 1) {
        // P' = exp(32*s - 32), causal mask, bf16 store + per-row partial sums.
        u16* P = (u16*)C;
#pragma unroll
        for (int m = 0; m < 4; ++m) {
#pragma unroll
            for (int r = 0; r < 4; ++r) {
                int row = tm + wr + m * 16 + fq * 4 + r;
                float rs = 0.f;
#pragma unroll
                for (int n = 0; n < 4; ++n) {
                    int col = tn + wc + n * 16 + fr;
                    float p = (col <= row) ? __expf(32.f * acc[m][n][r] - 32.f) : 0.f;
                    u16 pb = f2bf(p);
                    P[(size_t)row * 2048 + col] = pb;
                    rs += bf2f(pb);                 // sum the value PV will consume
                }
                rs += __shfl_xor(rs, 1);
                rs += __shfl_xor(rs, 2);
                rs += __shfl_xor(rs, 4);
                rs += __shfl_xor(rs, 8);
                if (fr == 0)
                    psum[((size_t)bz * 32 + bx * 2 + (wave & 1)) * 2048 + row] = rs;
            }
        }
    } else if (MODE == 2) {
        // compute rowinv for this row band from psum (L2-hot, 1 MB total)
        float* rinv = (float*)lds;   // safe: all LDS reads retired at last barrier
        if (tid < 128) {
            int row = tm + tid;
            int ns = 2 * (by + 1);
            float s = 0.f;
            for (int j = 0; j < ns; ++j)
                s += psum[((size_t)bz * 32 + j) * 2048 + row];
            rinv[tid] = 1.f / s;
        }
        __syncthreads();
#pragma unroll
        for (int m = 0; m < 4; ++m) {
#pragma unroll
            for (int r = 0; r < 4; ++r) {
                int lrow = wr + m * 16 + fq * 4 + r;
                float inv = rinv[lrow];
                int row = tm + lrow;
#pragma unroll
                for (int n = 0; n < 4; ++n) {
                    int col = tn + wc + n * 16 + fr;
                    C[(size_t)row * ldc + col] = acc[m][n][r] * inv;
                }
            }
        }
    } else {
#pragma unroll
        for (int m = 0; m < 4; ++m)
#pragma unroll
            for (int n = 0; n < 4; ++n)
#pragma unroll
                for (int r = 0; r < 4; ++r) {
                    int row = tm + wr + m * 16 + fq * 4 + r;
                    int col = tn + wc + n * 16 + fr;
                    C[(size_t)row * ldc + col] = (CT)f2bf(acc[m][n][r]);
                }
    }
}

// ---------- RoPE + L2 norm * sqk*32, in-place on qk[8192][2048] ----------
__global__ __launch_bounds__(256)
void rope_norm(u16* __restrict__ qk, const float* __restrict__ sqk,
               const u16* __restrict__ trig) {
    const int row = blockIdx.x;        // b*2048 + t
    const int t = row & 2047;
    u16* qp = qk + (size_t)row * 2048;
    u16* kp = qp + 1024;
    const u16* tb = trig + (size_t)t * 1024;
    const int d = threadIdx.x << 1;    // 0,2,...,510

    union U2 { uint u; u16 h[2]; };
    U2 qc0, qc1, kc0, kc1, cc, ss;
    qc0.u = *reinterpret_cast<const uint*>(qp + d);
    qc1.u = *reinterpret_cast<const uint*>(qp + 512 + d);
    kc0.u = *reinterpret_cast<const uint*>(kp + d);
    kc1.u = *reinterpret_cast<const uint*>(kp + 512 + d);
    cc.u  = *reinterpret_cast<const uint*>(tb + d);
    ss.u  = *reinterpret_cast<const uint*>(tb + 512 + d);

    float nq0[2], nq1[2], nk0[2], nk1[2];
    float ssq_q = 0.f, ssq_k = 0.f;
#pragma unroll
    for (int j = 0; j < 2; ++j) {
        float c = h2f(cc.h[j]), s = h2f(ss.h[j]);
        float q0 = bf2f(qc0.h[j]), q1 = bf2f(qc1.h[j]);
        float k0 = bf2f(kc0.h[j]), k1 = bf2f(kc1.h[j]);
        nq0[j] = q0 * c - q1 * s;
        nq1[j] = q1 * c + q0 * s;
        nk0[j] = k0 * c - k1 * s;
        nk1[j] = k1 * c + k0 * s;
        ssq_q += nq0[j] * nq0[j] + nq1[j] * nq1[j];
        ssq_k += nk0[j] * nk0[j] + nk1[j] * nk1[j];
    }

#pragma unroll
    for (int off = 32; off; off >>= 1) {
        ssq_q += __shfl_xor(ssq_q, off);
        ssq_k += __shfl_xor(ssq_k, off);
    }
    __shared__ float red[8];
    int wave = threadIdx.x >> 6, lane = threadIdx.x & 63;
    if (lane == 0) { red[wave] = ssq_q; red[4 + wave] = ssq_k; }
    __syncthreads();
    float rq = rsqrtf(red[0] + red[1] + red[2] + red[3]);
    float rk = rsqrtf(red[4] + red[5] + red[6] + red[7]);

    float2 sq0 = *reinterpret_cast<const float2*>(sqk + d);
    float2 sq1 = *reinterpret_cast<const float2*>(sqk + 512 + d);
    float s0[2] = {sq0.x * 32.f, sq0.y * 32.f};
    float s1[2] = {sq1.x * 32.f, sq1.y * 32.f};

    U2 oq0, oq1, ok0, ok1;
#pragma unroll
    for (int j = 0; j < 2; ++j) {
        oq0.h[j] = f2bf(nq0[j] * rq * s0[j]);
        oq1.h[j] = f2bf(nq1[j] * rq * s1[j]);
        ok0.h[j] = f2bf(nk0[j] * rk * s0[j]);
        ok1.h[j] = f2bf(nk1[j] * rk * s1[j]);
    }
    *reinterpret_cast<uint*>(qp + d)       = oq0.u;
    *reinterpret_cast<uint*>(qp + 512 + d) = oq1.u;
    *reinterpret_cast<uint*>(kp + d)       = ok0.u;
    *reinterpret_cast<uint*>(kp + 512 + d) = ok1.u;
}

// ---------- host launcher ----------
extern "C" void kernel_launch(void* const* d_in, const int* in_sizes, int n_in,
                              void* d_out, int out_size, void* d_ws, size_t ws_size,
                              hipStream_t stream) {
    const float* x   = (const float*)d_in[0];   // [4,2048,1024]
    const float* w   = (const float*)d_in[1];   // [3072,1024]
    const float* sqk = (const float*)d_in[2];   // [1024]
    float* out = (float*)d_out;

    const size_t SZ_XB  = (size_t)8192 * 1024 * 2;
    const size_t SZ_WB  = (size_t)3072 * 1024 * 2;
    const size_t SZ_QK  = (size_t)8192 * 2048 * 2;
    const size_t SZ_VT  = (size_t)4 * 1024 * 2048 * 2;
    const size_t SZ_P   = (size_t)4 * 2048 * 2048 * 2;    // P' bf16
    const size_t SZ_TR  = (size_t)2048 * 1024 * 2;
    const size_t SZ_PS  = (size_t)4 * 32 * 2048 * 4;      // psum fp32
    if (ws_size < SZ_XB + SZ_WB + SZ_QK + SZ_VT + SZ_P + SZ_TR + SZ_PS) return;

    char* ws = (char*)d_ws;
    u16*   xb   = (u16*)ws;   ws += SZ_XB;
    u16*   wb   = (u16*)ws;   ws += SZ_WB;
    u16*   qk   = (u16*)ws;   ws += SZ_QK;
    u16*   VT   = (u16*)ws;   ws += SZ_VT;
    u16*   P    = (u16*)ws;   ws += SZ_P;
    u16*   trig = (u16*)ws;   ws += SZ_TR;
    float* psum = (float*)ws;

    // fused prep: x->bf16, w->bf16, trig table
    prep<<<4864, 256, 0, stream>>>(x, w, xb, wb, trig);

    // QKV: qk[8192][2048] (Q|K) + VT[b][1024][2048] (V^T direct)
    gemm_bt<0, u16><<<dim3(1536, 1, 1), 256, 0, stream>>>(
        xb, wb, qk, VT, nullptr, 1024, 1024, 1024, 2048, 0, 0, 0);

    rope_norm<<<8192, 256, 0, stream>>>(qk, sqk, trig);

    // S -> P' = exp(32s-32) bf16 + psum row partial sums; batch->XCD-pair locality
    gemm_bt<1, u16><<<dim3(544, 1, 1), 256, 0, stream>>>(
        qk, qk + 1024, P, nullptr, psum, 1024, 2048, 2048, 2048,
        (long)2048 * 2048, (long)2048 * 2048, (long)2048 * 2048);

    // out = (P' @ V) * rowinv (rowinv computed in-kernel from psum)
    gemm_bt<2, float><<<dim3(512, 1, 1), 256, 0, stream>>>(
        P, VT, out, nullptr, psum, 2048, 2048, 2048, 1024,
        (long)2048 * 2048, (long)1024 * 2048, (long)2048 * 1024);
}